// Round 20
// baseline (91.324 us; speedup 1.0000x reference)
//
#include <hip/hip_runtime.h>

#define BROWS 131072
#define DD 64
#define INF 128
#define NOUT 8
#define GJP 65    // padded f32 stride for the in-place GJ matrix (prep only)
#define NCHEAP 15 // hi-only iterations
#define NFULL 1   // full two-plane iterations after the bridge

// packed fragment tables in ws (u32 words). idx = ((ki*4+rt)*64+lane)*4+p
#define PK_RH   0
#define PK_RL   2048
#define PK_W1H  4096
#define PK_W1L  8192
#define PK_UWH  12288
#define PK_UWL  14336
#define PK_WSH  16384
#define PK_WSL  18432
#define PK_PWH  20480
#define PK_PWL  20992

typedef __attribute__((ext_vector_type(8))) short bf16x8;  // 4 VGPR A/B frag
typedef __attribute__((ext_vector_type(4))) float f32x4;   // 16x16 C/D frag

union FragU { uint4 u; bf16x8 f; };

// sigma: direct-feed row permutation (r15-verified).
__host__ __device__ __forceinline__ int sig(int r) {
  const int base = r & 32;
  const int kg = (r >> 3) & 3;
  const int s  = r & 7;
  return base + ((s < 4) ? (4*kg + s) : (16 + 4*kg + (s - 4)));
}

__device__ __forceinline__ unsigned pk2(float a, float b) {
  return (__float_as_uint(a) >> 16) | (__float_as_uint(b) & 0xFFFF0000u);
}
__device__ __forceinline__ float res_lo(float v) {
  return v - __uint_as_float(__float_as_uint(v) & 0xFFFF0000u);
}
__device__ __forceinline__ unsigned cvtpk(float a, float b) {
  unsigned w; asm("v_cvt_pk_bf16_f32 %0, %1, %2" : "=v"(w) : "v"(a), "v"(b)); return w;
}
__device__ __forceinline__ unsigned cvtpk_abs(float a, float b) {
  unsigned w; asm("v_cvt_pk_bf16_f32 %0, abs(%1), abs(%2)" : "=v"(w) : "v"(a), "v"(b)); return w;
}
__device__ __forceinline__ float lo_f(unsigned w) { return __uint_as_float(w << 16); }
__device__ __forceinline__ float hi_f(unsigned w) { return __uint_as_float(w & 0xFFFF0000u); }

__device__ __forceinline__ bf16x8 frag4(unsigned a, unsigned b, unsigned c, unsigned d) {
  FragU t; t.u.x = a; t.u.y = b; t.u.z = c; t.u.w = d; return t.f;
}
__device__ __forceinline__ f32x4 MF16(bf16x8 a, bf16x8 b, f32x4 c) {
  return __builtin_amdgcn_mfma_f32_16x16x32_bf16(a, b, c, 0, 0, 0);
}

// Direct C/D->B feed (zero lane ops): fragment ki = tiles 2ki, 2ki+1.
__device__ __forceinline__ void direct_frags(const unsigned P[4][2], bf16x8& f0, bf16x8& f1) {
  f0 = frag4(P[0][0], P[0][1], P[1][0], P[1][1]);
  f1 = frag4(P[2][0], P[2][1], P[3][0], P[3][1]);
}

// cheap-phase pack: abs folded into cvt_pk input modifiers (2 ops/rt)
__device__ __forceinline__ void pack_hi_abs(const f32x4* a, unsigned P[4][2]) {
  #pragma unroll
  for (int rt = 0; rt < 4; ++rt) {
    P[rt][0] = cvtpk_abs(a[rt][0], a[rt][1]);
    P[rt][1] = cvtpk_abs(a[rt][2], a[rt][3]);
  }
}

// full two-plane pack, RNE hi + exact residual lo. MODE: 0 raw, 1 abs, 2 relu.
template<int MODE>
__device__ __forceinline__ void pack_full(const f32x4* a, unsigned Ph[4][2], unsigned Pl[4][2]) {
  #pragma unroll
  for (int rt = 0; rt < 4; ++rt) {
    float x0 = a[rt][0], x1 = a[rt][1], x2 = a[rt][2], x3 = a[rt][3];
    unsigned h0, h1;
    if (MODE == 1) {
      h0 = cvtpk_abs(x0, x1);  h1 = cvtpk_abs(x2, x3);
      x0 = fabsf(x0); x1 = fabsf(x1); x2 = fabsf(x2); x3 = fabsf(x3);
    } else if (MODE == 2) {
      x0 = fmaxf(x0,0.f); x1 = fmaxf(x1,0.f); x2 = fmaxf(x2,0.f); x3 = fmaxf(x3,0.f);
      h0 = cvtpk(x0, x1);  h1 = cvtpk(x2, x3);
    } else {
      h0 = cvtpk(x0, x1);  h1 = cvtpk(x2, x3);
    }
    Ph[rt][0] = h0;  Ph[rt][1] = h1;
    Pl[rt][0] = cvtpk(x0 - lo_f(h0), x1 - hi_f(h0));
    Pl[rt][1] = cvtpk(x2 - lo_f(h1), x3 - hi_f(h1));
  }
}

// B-fragment (hi,lo) from 8 explicit f32 values (x rows) — prologue only.
__device__ __forceinline__ void build_b8(const float* v, bf16x8& fh, bf16x8& fl) {
  FragU h, l;
  h.u.x = pk2(v[0],v[1]); h.u.y = pk2(v[2],v[3]);
  h.u.z = pk2(v[4],v[5]); h.u.w = pk2(v[6],v[7]);
  l.u.x = pk2(res_lo(v[0]),res_lo(v[1])); l.u.y = pk2(res_lo(v[2]),res_lo(v[3]));
  l.u.z = pk2(res_lo(v[4]),res_lo(v[5])); l.u.w = pk2(res_lo(v[6]),res_lo(v[7]));
  fh = h.f; fl = l.f;
}

// acc[rt] += A @ B (3-term), A from packed table, B in registers.
__device__ __forceinline__ void product3reg(f32x4* acc, const unsigned* TH,
    const unsigned* TL, bf16x8 b0h, bf16x8 b1h, bf16x8 b0l, bf16x8 b1l, int lane) {
  #pragma unroll
  for (int ki = 0; ki < 2; ++ki) {
    const bf16x8 bh = ki ? b1h : b0h;
    const bf16x8 bl = ki ? b1l : b0l;
    #pragma unroll
    for (int rt = 0; rt < 4; ++rt) {
      FragU ah, al;
      ah.u = *reinterpret_cast<const uint4*>(TH + ((ki*4+rt)*64 + lane)*4);
      al.u = *reinterpret_cast<const uint4*>(TL + ((ki*4+rt)*64 + lane)*4);
      acc[rt] = MF16(ah.f, bh, acc[rt]);
      acc[rt] = MF16(ah.f, bl, acc[rt]);
      acc[rt] = MF16(al.f, bh, acc[rt]);
    }
  }
}

// acc[rt] += A @ B (2-term, A-residual dropped). Post-solve products only.
__device__ __forceinline__ void product2reg(f32x4* acc, const unsigned* TH,
    bf16x8 b0h, bf16x8 b1h, bf16x8 b0l, bf16x8 b1l, int lane) {
  #pragma unroll
  for (int ki = 0; ki < 2; ++ki) {
    const bf16x8 bh = ki ? b1h : b0h;
    const bf16x8 bl = ki ? b1l : b0l;
    #pragma unroll
    for (int rt = 0; rt < 4; ++rt) {
      FragU ah;
      ah.u = *reinterpret_cast<const uint4*>(TH + ((ki*4+rt)*64 + lane)*4);
      acc[rt] = MF16(ah.f, bh, acc[rt]);
      acc[rt] = MF16(ah.f, bl, acc[rt]);
    }
  }
}

// ---------------------------------------------------------------------------
// Prep. Tables absorb sigma (r15). Block 13's GJ now runs 2 barriers/pivot
// with the thread-owned column slice register-resident (LDS = publish mirror).
// ---------------------------------------------------------------------------
__global__ __launch_bounds__(512) void k_prep(
    const float* __restrict__ W1, const float* __restrict__ Uw,
    const float* __restrict__ Aw, const float* __restrict__ Bw,
    const float* __restrict__ Pw, unsigned* __restrict__ pk) {
  const int b = blockIdx.x, tid = threadIdx.x;

  if (b < 8) {          // ---- W1': row-permuted only
    const int e = b * 512 + tid;            // [0, 4096)
    const int p = e & 3, lane = (e >> 2) & 63, rt = (e >> 8) & 3, ki = e >> 10;
    const int j = sig(16*rt + (lane & 15));
    const int k = 32*ki + 8*(lane >> 4) + 2*p;
    const float v0 = W1[j*INF + k], v1 = W1[j*INF + k + 1];
    pk[PK_W1H + e] = pk2(v0, v1);
    pk[PK_W1L + e] = pk2(res_lo(v0), res_lo(v1));
    return;
  }
  if (b < 12) {         // ---- Uw': (sig, sig^2)
    const int e = (b - 8) * 512 + tid;      // [0, 2048)
    const int p = e & 3, lane = (e >> 2) & 63, rt = (e >> 8) & 3, ki = e >> 10;
    const int j = sig(16*rt + (lane & 15));
    const int kc = 32*ki + 8*(lane >> 4) + 2*p;
    const int k0 = sig(sig(kc)), k1 = sig(sig(kc + 1));
    const float v0 = Uw[j*DD + k0], v1 = Uw[j*DD + k1];
    pk[PK_UWH + e] = pk2(v0, v1);
    pk[PK_UWL + e] = pk2(res_lo(v0), res_lo(v1));
    return;
  }
  if (b == 12) {        // ---- Pw': col sig^2 (rows 8..15 zero)
    if (tid < 512) {
      const int e = tid;                    // [0, 512)
      const int p = e & 3, lane = (e >> 2) & 63, ki = e >> 8;
      const int o = lane & 15;
      const int kc = 32*ki + 8*(lane >> 4) + 2*p;
      const int k0 = sig(sig(kc)), k1 = sig(sig(kc + 1));
      const float v0 = (o < NOUT) ? Pw[o*DD + k0] : 0.0f;
      const float v1 = (o < NOUT) ? Pw[o*DD + k1] : 0.0f;
      pk[PK_PWH + e] = pk2(v0, v1);
      pk[PK_PWL + e] = pk2(res_lo(v0), res_lo(v1));
    }
    return;
  }

  // ---- block 13: W, f32 GJ inversion (2-barrier), pack W' + R'
  __shared__ float As[DD * DD];
  __shared__ float MT[DD * GJP];     // MT[k*GJP+t] = M[t][k]
  __shared__ float Wls[DD * GJP];    // Wls[k*GJP+t] = W[t][k]
  const int t = tid & 63;
  const int cg = tid >> 6;

  #pragma unroll
  for (int q = 0; q < 8; ++q) As[q * 512 + tid] = Aw[q * 512 + tid];
  __syncthreads();

  float m[8];   // own slice: M rows 8cg..8cg+7 of column t, register-resident
  {
    float s[8];
    #pragma unroll
    for (int q = 0; q < 8; ++q) s[q] = 0.0f;
    for (int i = 0; i < DD; ++i) {
      const float at = As[i*DD + t];
      const float* ak = As + i*DD + 8*cg;
      #pragma unroll
      for (int q = 0; q < 8; ++q) s[q] = fmaf(at, ak[q], s[q]);
    }
    #pragma unroll
    for (int q = 0; q < 8; ++q) {
      const int k = 8*cg + q;
      const float w = ((t == k) ? 0.9f : 0.0f) - s[q] + Bw[t*DD + k] - Bw[k*DD + t];
      Wls[k*GJP + t] = w;
      m[q] = ((t == k) ? 2.0f : 0.0f) - w;
      MT[k*GJP + t] = m[q];
    }
  }
  __syncthreads();

  // 2-barrier GJ: read {praw, f, mc[8]} -> barrier -> scale/eliminate in regs
  // -> publish 8 writes -> barrier.  Algebra identical to the 3-phase variant.
  #pragma unroll 1
  for (int c = 0; c < DD; ++c) {
    const float praw = MT[c*GJP + c];       // broadcast
    const float f    = MT[c*GJP + t];       // lane-consecutive
    float mc[8];
    #pragma unroll
    for (int q = 0; q < 8; ++q) mc[q] = MT[(8*cg + q)*GJP + c];  // broadcast
    __syncthreads();                        // (A) all reads complete
    const float p = 1.0f / praw;
    if (t == c) {                           // own column IS the pivot column
      #pragma unroll
      for (int q = 0; q < 8; ++q) {
        const int j = 8*cg + q;
        m[q] = (j == c) ? p : m[q] * p;
        MT[j*GJP + c] = m[q];
      }
    } else {
      const float g = f * p;
      #pragma unroll
      for (int q = 0; q < 8; ++q) {
        const int j = 8*cg + q;
        const float mce = (j == c) ? 1.0f : mc[q];   // scaled pivot col = g*mce
        m[q] = fmaf(-g, mce, (j == c) ? 0.0f : m[q]);
        MT[j*GJP + t] = m[q];
      }
    }
    __syncthreads();                        // (B) writes visible
  }
  // MT[a*GJP+b] = Minv[b][a]

  #pragma unroll
  for (int e = 0; e < 2048; e += 512) {
    const int ee = e + tid;
    const int p = ee & 3, lane = (ee >> 2) & 63, rt = (ee >> 8) & 3, ki = ee >> 10;
    const int j = sig(16*rt + (lane & 15));
    const int kc = 32*ki + 8*(lane >> 4) + 2*p;
    const int k0 = sig(sig(kc)), k1 = sig(sig(kc + 1));
    {  // W': W[j][k] = Wls[k*GJP + j]
      const float v0 = Wls[k0*GJP + j], v1 = Wls[k1*GJP + j];
      pk[PK_WSH + ee] = pk2(v0, v1);
      pk[PK_WSL + ee] = pk2(res_lo(v0), res_lo(v1));
    }
    {  // R': 2*Minv[j][k] - delta(j,k) = 2*MT[k*GJP+j] - delta
      const float v0 = 2.0f*MT[k0*GJP + j] - ((k0 == j) ? 1.0f : 0.0f);
      const float v1 = 2.0f*MT[k1*GJP + j] - ((k1 == j) ? 1.0f : 0.0f);
      pk[PK_RH + ee] = pk2(v0, v1);
      pk[PK_RL + ee] = pk2(res_lo(v0), res_lo(v1));
    }
  }
}

// ---------------------------------------------------------------------------
// Fused solve — zero LDS, zero permlane (sigma-permuted state space),
// 15 cheap + bridge + 1 full + final = 18 PR steps; zn/out products 2-term.
// ---------------------------------------------------------------------------
__global__ __launch_bounds__(256) void k_solve(
    const float* __restrict__ x,  const float* __restrict__ b1,
    const float* __restrict__ Ub, const float* __restrict__ Pb,
    const unsigned* __restrict__ pk, float* __restrict__ out) {
  const int tid  = threadIdx.x;
  const int lane = tid & 63, wv = tid >> 6;
  const int l15  = lane & 15, kg = lane >> 4;
  const size_t ncol = (size_t)blockIdx.x * 64 + wv * 16 + l15;

  // R' fragments resident in registers
  FragU rFh[4][2], rFl[4][2];
  #pragma unroll
  for (int rt = 0; rt < 4; ++rt)
    #pragma unroll
    for (int ki = 0; ki < 2; ++ki) {
      rFh[rt][ki].u = *reinterpret_cast<const uint4*>(pk + PK_RH + ((ki*4+rt)*64 + lane)*4);
      rFl[rt][ki].u = *reinterpret_cast<const uint4*>(pk + PK_RL + ((ki*4+rt)*64 + lane)*4);
    }

  // ---- h' = relu(W1' x^T + b1'): C-init at sig(row)
  f32x4 hC[4];
  #pragma unroll
  for (int rt = 0; rt < 4; ++rt)
    #pragma unroll
    for (int r = 0; r < 4; ++r)
      hC[rt][r] = b1[sig(16*rt + 4*kg + r)];
  #pragma unroll
  for (int ki = 0; ki < 4; ++ki) {
    const float* xp = x + ncol * INF + 32*ki + 8*kg;
    float bv[8];
    #pragma unroll
    for (int s = 0; s < 8; ++s) bv[s] = xp[s];
    bf16x8 Bh, Bl; build_b8(bv, Bh, Bl);
    #pragma unroll
    for (int rt = 0; rt < 4; ++rt) {
      FragU ah, al;
      ah.u = *reinterpret_cast<const uint4*>(pk + PK_W1H + ((ki*4+rt)*64 + lane)*4);
      al.u = *reinterpret_cast<const uint4*>(pk + PK_W1L + ((ki*4+rt)*64 + lane)*4);
      hC[rt] = MF16(ah.f, Bh, hC[rt]);
      hC[rt] = MF16(ah.f, Bl, hC[rt]);
      hC[rt] = MF16(al.f, Bh, hC[rt]);
    }
  }

  unsigned Ph[4][2], Pl[4][2];
  bf16x8 Bh0, Bh1, Bl0, Bl1;

  // ---- bias' = Uw' relu(h') + Ub'  (3-term: pre-solve, amplified)
  f32x4 biasC[4];
  #pragma unroll
  for (int rt = 0; rt < 4; ++rt)
    #pragma unroll
    for (int r = 0; r < 4; ++r)
      biasC[rt][r] = Ub[sig(16*rt + 4*kg + r)];
  pack_full<2>(hC, Ph, Pl);
  direct_frags(Ph, Bh0, Bh1); direct_frags(Pl, Bl0, Bl1);
  product3reg(biasC, pk + PK_UWH, pk + PK_UWL, Bh0, Bh1, Bl0, Bl1, lane);

  // ---- c2' = R' bias' + bias'  (3-term)
  f32x4 c2a[4];
  #pragma unroll
  for (int rt = 0; rt < 4; ++rt) c2a[rt] = biasC[rt];
  pack_full<0>(biasC, Ph, Pl);
  direct_frags(Ph, Bh0, Bh1); direct_frags(Pl, Bl0, Bl1);
  #pragma unroll
  for (int ki = 0; ki < 2; ++ki) {
    const bf16x8 bh = ki ? Bh1 : Bh0;
    const bf16x8 bl = ki ? Bl1 : Bl0;
    #pragma unroll
    for (int rt = 0; rt < 4; ++rt) {
      c2a[rt] = MF16(rFh[rt][ki].f, bh, c2a[rt]);
      c2a[rt] = MF16(rFh[rt][ki].f, bl, c2a[rt]);
      c2a[rt] = MF16(rFl[rt][ki].f, bh, c2a[rt]);
    }
  }

  // ---- cheap phase: 15 iterations, Rh only (8 MFMA + 8 cvt_pk, no swaps)
  unsigned P[4][2];
  bf16x8 B0, B1;
  pack_hi_abs(c2a, P); direct_frags(P, B0, B1);     // |u1| = |c2|
  f32x4 u[4];
  #pragma unroll 1
  for (int it = 0; it < NCHEAP; ++it) {
    #pragma unroll
    for (int rt = 0; rt < 4; ++rt) {
      u[rt] = MF16(rFh[rt][0].f, B0, c2a[rt]);
      u[rt] = MF16(rFh[rt][1].f, B1, u[rt]);
    }
    pack_hi_abs(u, P); direct_frags(P, B0, B1);
  }

  // ---- bridge: 2-term (Rh+Rl) on hi state
  #pragma unroll
  for (int rt = 0; rt < 4; ++rt) {
    u[rt] = MF16(rFh[rt][0].f, B0, c2a[rt]);
    u[rt] = MF16(rFl[rt][0].f, B0, u[rt]);
    u[rt] = MF16(rFh[rt][1].f, B1, u[rt]);
    u[rt] = MF16(rFl[rt][1].f, B1, u[rt]);
  }

  // ---- full phase: 1 iteration 3-term, then final step
  pack_full<1>(u, Ph, Pl);
  direct_frags(Ph, Bh0, Bh1); direct_frags(Pl, Bl0, Bl1);
  #pragma unroll 1
  for (int it = 0; it < NFULL; ++it) {
    #pragma unroll
    for (int rt = 0; rt < 4; ++rt) {
      u[rt] = MF16(rFh[rt][0].f, Bh0, c2a[rt]);
      u[rt] = MF16(rFh[rt][0].f, Bl0, u[rt]);
      u[rt] = MF16(rFl[rt][0].f, Bh0, u[rt]);
      u[rt] = MF16(rFh[rt][1].f, Bh1, u[rt]);
      u[rt] = MF16(rFh[rt][1].f, Bl1, u[rt]);
      u[rt] = MF16(rFl[rt][1].f, Bh1, u[rt]);
    }
    pack_full<1>(u, Ph, Pl);
    direct_frags(Ph, Bh0, Bh1); direct_frags(Pl, Bl0, Bl1);
  }
  #pragma unroll
  for (int rt = 0; rt < 4; ++rt) {
    u[rt] = MF16(rFh[rt][0].f, Bh0, c2a[rt]);
    u[rt] = MF16(rFh[rt][0].f, Bl0, u[rt]);
    u[rt] = MF16(rFl[rt][0].f, Bh0, u[rt]);
    u[rt] = MF16(rFh[rt][1].f, Bh1, u[rt]);
    u[rt] = MF16(rFh[rt][1].f, Bl1, u[rt]);
    u[rt] = MF16(rFl[rt][1].f, Bh1, u[rt]);
  }

  // ---- zn' = relu(W' relu(u_final) + bias')  (2-term: post-solve)
  pack_full<2>(u, Ph, Pl);
  direct_frags(Ph, Bh0, Bh1); direct_frags(Pl, Bl0, Bl1);
  f32x4 zn[4];
  #pragma unroll
  for (int rt = 0; rt < 4; ++rt) zn[rt] = biasC[rt];
  product2reg(zn, pk + PK_WSH, Bh0, Bh1, Bl0, Bl1, lane);

  // ---- out = relu(zn) @ Pw'^T + Pb  (2-term: Pw-lo dropped)
  pack_full<2>(zn, Ph, Pl);
  direct_frags(Ph, Bh0, Bh1); direct_frags(Pl, Bl0, Bl1);
  f32x4 oC = (f32x4){0.f, 0.f, 0.f, 0.f};
  if (kg < 2) {
    const float4 pb = *reinterpret_cast<const float4*>(Pb + 4*kg);
    oC[0] = pb.x; oC[1] = pb.y; oC[2] = pb.z; oC[3] = pb.w;
  }
  #pragma unroll
  for (int ki = 0; ki < 2; ++ki) {
    const bf16x8 bh = ki ? Bh1 : Bh0;
    const bf16x8 bl = ki ? Bl1 : Bl0;
    FragU ah;
    ah.u = *reinterpret_cast<const uint4*>(pk + PK_PWH + (ki*64 + lane)*4);
    oC = MF16(ah.f, bh, oC);
    oC = MF16(ah.f, bl, oC);
  }
  if (kg < 2) {
    float4* op = reinterpret_cast<float4*>(out + ncol * NOUT + 4*kg);
    *op = make_float4(oC[0], oC[1], oC[2], oC[3]);
  }
}

extern "C" void kernel_launch(void* const* d_in, const int* in_sizes, int n_in,
                              void* d_out, int out_size, void* d_ws, size_t ws_size,
                              hipStream_t stream) {
  const float* x  = (const float*)d_in[0];
  const float* W1 = (const float*)d_in[1];
  const float* b1 = (const float*)d_in[2];
  const float* Uw = (const float*)d_in[3];
  const float* Ub = (const float*)d_in[4];
  const float* Aw = (const float*)d_in[5];
  const float* Bw = (const float*)d_in[6];
  const float* Pw = (const float*)d_in[7];
  const float* Pb = (const float*)d_in[8];
  float* outp = (float*)d_out;
  unsigned* pk = (unsigned*)d_ws;                 // 86 KB packed fragment tables

  k_prep  <<<14, 512, 0, stream>>>(W1, Uw, Aw, Bw, Pw, pk);
  k_solve <<<BROWS/64, 256, 0, stream>>>(x, b1, Ub, Pb, pk, outp);
}